// Round 11
// baseline (350.529 us; speedup 1.0000x reference)
//
#include <hip/hip_runtime.h>

#define TOKENS 16384
#define DDIM 4096
#define RANK 32
#define TOPK 8
#define KCH 8                        // K-chunks -> y_part planes
#define KSTEPS ((DDIM / KCH) / 32)   // 16 MFMA K-steps per chunk
#define TAU 2e-3f                    // routing-gap margin: flag if below

typedef __attribute__((ext_vector_type(8))) short bf16x8;  // 8 bf16 (4 VGPR)
typedef __attribute__((ext_vector_type(4))) float f32x4;

// ---------------- K0: split A (fp32) into hi/lo bf16 planes ----------------
__global__ __launch_bounds__(256) void k0_splitA(const float* __restrict__ A,
                                                 ushort* __restrict__ Ah,
                                                 ushort* __restrict__ Al) {
  const int i = blockIdx.x * 256 + threadIdx.x;  // 0 .. RANK*DDIM-1
  const float a = A[i];
  const unsigned ab = __float_as_uint(a);
  const float hf = __uint_as_float(ab & 0xFFFF0000u);
  const float r = a - hf;
  Ah[i] = (ushort)(ab >> 16);
  Al[i] = (ushort)(__float_as_uint(r) >> 16);
}

// ---------------- K1: y_part[kc][t][r] via mfma_f32_16x16x32_bf16 ----------
// y ~= xh*Ah + xh*Al + xl*Ah (delta ~3e-5). Values are plenty accurate for
// the output (out err ~5e-6); ROUTING near boundaries is fixed up by k2b.
__global__ __launch_bounds__(256) void k1_mfma(const float* __restrict__ x,
                                               const ushort* __restrict__ Ah,
                                               const ushort* __restrict__ Al,
                                               float* __restrict__ y_part) {
  const int tid = threadIdx.x;
  const int lane = tid & 63;
  const int wv = tid >> 6;
  const int t0 = blockIdx.x * 64 + wv * 16;
  const int kc = blockIdx.y;
  const int k0 = kc * (DDIM / KCH);

  const int mrow = lane & 15;  // token (A-op) / rank (B-op)
  const int kg = lane >> 4;    // k-group of 8 dims

  f32x4 acc0 = {0.f, 0.f, 0.f, 0.f};  // ranks 0..15
  f32x4 acc1 = {0.f, 0.f, 0.f, 0.f};  // ranks 16..31

  const float* xp = &x[(size_t)(t0 + mrow) * DDIM + k0 + kg * 8];
  const ushort* ah0 = &Ah[(size_t)mrow * DDIM + k0 + kg * 8];
  const ushort* ah1 = &Ah[(size_t)(mrow + 16) * DDIM + k0 + kg * 8];
  const ushort* al0 = &Al[(size_t)mrow * DDIM + k0 + kg * 8];
  const ushort* al1 = &Al[(size_t)(mrow + 16) * DDIM + k0 + kg * 8];

#pragma unroll 2
  for (int ks = 0; ks < KSTEPS; ++ks) {
    const float4 xa = *reinterpret_cast<const float4*>(xp + ks * 32);
    const float4 xb = *reinterpret_cast<const float4*>(xp + ks * 32 + 4);
    const bf16x8 bh0 = *reinterpret_cast<const bf16x8*>(ah0 + ks * 32);
    const bf16x8 bh1 = *reinterpret_cast<const bf16x8*>(ah1 + ks * 32);
    const bf16x8 bl0 = *reinterpret_cast<const bf16x8*>(al0 + ks * 32);
    const bf16x8 bl1 = *reinterpret_cast<const bf16x8*>(al1 + ks * 32);

    const float xf[8] = {xa.x, xa.y, xa.z, xa.w, xb.x, xb.y, xb.z, xb.w};
    bf16x8 xh, xl;
#pragma unroll
    for (int j = 0; j < 8; ++j) {  // constant indices only (no scratch)
      const unsigned b = __float_as_uint(xf[j]);
      xh[j] = (short)(b >> 16);
      const float r = xf[j] - __uint_as_float(b & 0xFFFF0000u);
      xl[j] = (short)(__float_as_uint(r) >> 16);
    }

    acc0 = __builtin_amdgcn_mfma_f32_16x16x32_bf16(xh, bh0, acc0, 0, 0, 0);
    acc1 = __builtin_amdgcn_mfma_f32_16x16x32_bf16(xh, bh1, acc1, 0, 0, 0);
    acc0 = __builtin_amdgcn_mfma_f32_16x16x32_bf16(xh, bl0, acc0, 0, 0, 0);
    acc1 = __builtin_amdgcn_mfma_f32_16x16x32_bf16(xh, bl1, acc1, 0, 0, 0);
    acc0 = __builtin_amdgcn_mfma_f32_16x16x32_bf16(xl, bh0, acc0, 0, 0, 0);
    acc1 = __builtin_amdgcn_mfma_f32_16x16x32_bf16(xl, bh1, acc1, 0, 0, 0);
  }

  // D: token = t0 + kg*4 + i, rank = mrow (acc0) / mrow+16 (acc1)
  float* yp = &y_part[((size_t)kc * TOKENS + t0 + kg * 4) * RANK + mrow];
#pragma unroll
  for (int i = 0; i < 4; ++i) {
    yp[(size_t)i * RANK] = acc0[i];
    yp[(size_t)i * RANK + 16] = acc1[i];
  }
}

// ---------------- K2: reduce, top-8 + gap margin; dense flag write --------
// flag[t] is written for EVERY token (0/1): no atomics, no init, replay-safe.
__global__ __launch_bounds__(64) void k2_topk(const float* __restrict__ y_part,
                                              const float* __restrict__ dbias,
                                              float* __restrict__ w,
                                              int* __restrict__ flag) {
  const int t = blockIdx.x * 64 + threadIdx.x;
  float yv[RANK];
#pragma unroll
  for (int r = 0; r < RANK; ++r) yv[r] = 0.f;
  for (int c = 0; c < KCH; ++c) {
    const float* yp = &y_part[((size_t)c * TOKENS + t) * RANK];
#pragma unroll
    for (int q = 0; q < RANK / 4; ++q) {
      const float4 v = reinterpret_cast<const float4*>(yp)[q];
      yv[q * 4 + 0] += v.x; yv[q * 4 + 1] += v.y;
      yv[q * 4 + 2] += v.z; yv[q * 4 + 3] += v.w;
    }
  }

  float ab[RANK];
#pragma unroll
  for (int r = 0; r < RANK; ++r) ab[r] = fabsf(yv[r] + dbias[r]);

  unsigned mask = 0;
  float best8 = 0.f;
#pragma unroll
  for (int k = 0; k < TOPK; ++k) {
    float best = -1.f;
    int bi = 0;
#pragma unroll
    for (int r = 0; r < RANK; ++r) {
      // strict > keeps lowest index on ties == jax.lax.top_k stability
      const bool sel = (((mask >> r) & 1u) == 0u) && (ab[r] > best);
      best = sel ? ab[r] : best;
      bi = sel ? r : bi;
    }
    mask |= 1u << bi;
    best8 = best;
  }
  // 9th-largest: max over unselected
  float ninth = -1.f;
#pragma unroll
  for (int r = 0; r < RANK; ++r) {
    const bool un = ((mask >> r) & 1u) == 0u;
    ninth = (un && ab[r] > ninth) ? ab[r] : ninth;
  }
  flag[t] = (best8 - ninth < TAU) ? 1 : 0;  // split-y can't certify -> refine

  float* wp = &w[(size_t)t * RANK];
#pragma unroll
  for (int q = 0; q < RANK / 4; ++q) {
    float4 o;
    o.x = ((mask >> (q * 4 + 0)) & 1u) ? 2.0f * yv[q * 4 + 0] : 0.f;
    o.y = ((mask >> (q * 4 + 1)) & 1u) ? 2.0f * yv[q * 4 + 1] : 0.f;
    o.z = ((mask >> (q * 4 + 2)) & 1u) ? 2.0f * yv[q * 4 + 2] : 0.f;
    o.w = ((mask >> (q * 4 + 3)) & 1u) ? 2.0f * yv[q * 4 + 3] : 0.f;
    reinterpret_cast<float4*>(wp)[q] = o;
  }
}

// ---------------- K2b: exact fp32 re-route for flagged tokens -------------
// grid TOKENS/16 blocks x 64 thr; block scans 16 flags (uniform across the
// block -> no divergence hazard with __syncthreads). Per flagged token:
// rank=tid&31, seg=tid>>5 halves of 4096 dims; two-level fp32 sums
// (delta ~1e-7, the same risk profile as the passing fp32 rounds 1-8).
__global__ __launch_bounds__(64) void k2b_refine(const float* __restrict__ x,
                                                 const float* __restrict__ A,
                                                 const float* __restrict__ dbias,
                                                 const int* __restrict__ flag,
                                                 float* __restrict__ w) {
  __shared__ float part[2][RANK];
  __shared__ float yv_s[RANK];
  __shared__ unsigned mask_s;
  const int rank = threadIdx.x & 31;
  const int seg = threadIdx.x >> 5;
  const int tb = blockIdx.x * 16;

  for (int j = 0; j < 16; ++j) {
    const int t = tb + j;
    if (flag[t] == 0) continue;  // uniform branch (same t for whole block)

    const float* xr = &x[(size_t)t * DDIM + seg * 2048];
    const float* Ar = &A[(size_t)rank * DDIM + seg * 2048];
    float s = 0.f;
    for (int c = 0; c < 2048; c += 16) {
      float ss = 0.f;
#pragma unroll
      for (int u = 0; u < 16; ++u) ss = fmaf(xr[c + u], Ar[c + u], ss);
      s += ss;
    }
    part[seg][rank] = s;
    __syncthreads();
    if (threadIdx.x == 0) {
      float ab[RANK];
#pragma unroll
      for (int r = 0; r < RANK; ++r) {
        yv_s[r] = part[0][r] + part[1][r];
        ab[r] = fabsf(yv_s[r] + dbias[r]);
      }
      unsigned mask = 0;
#pragma unroll
      for (int k = 0; k < TOPK; ++k) {
        float best = -1.f;
        int bi = 0;
#pragma unroll
        for (int r = 0; r < RANK; ++r) {
          const bool sel = (((mask >> r) & 1u) == 0u) && (ab[r] > best);
          best = sel ? ab[r] : best;
          bi = sel ? r : bi;
        }
        mask |= 1u << bi;
      }
      mask_s = mask;
    }
    __syncthreads();
    if (threadIdx.x < 32) {
      w[(size_t)t * RANK + rank] =
          ((mask_s >> rank) & 1u) ? 2.0f * yv_s[rank] : 0.f;
    }
    __syncthreads();  // protect LDS reuse next flagged token
  }
}

// ---------------- K3: out[t][o] = sum_r w[t][r] * B[o][r] ----------------
#define K3_TOK 64

__global__ __launch_bounds__(256) void k3_out(const float* __restrict__ w,
                                              const float* __restrict__ B,
                                              float* __restrict__ out) {
  const int tid = threadIdx.x;
  const int c0 = blockIdx.x * 512 + tid * 2;
  const int tbase = blockIdx.y * K3_TOK;

  __shared__ float wl[K3_TOK * RANK];  // 8 KB

  float b0[RANK], b1[RANK];
#pragma unroll
  for (int q = 0; q < RANK / 4; ++q) {
    const float4 v0 = reinterpret_cast<const float4*>(&B[(size_t)c0 * RANK])[q];
    const float4 v1 =
        reinterpret_cast<const float4*>(&B[(size_t)(c0 + 1) * RANK])[q];
    b0[q * 4 + 0] = v0.x; b0[q * 4 + 1] = v0.y;
    b0[q * 4 + 2] = v0.z; b0[q * 4 + 3] = v0.w;
    b1[q * 4 + 0] = v1.x; b1[q * 4 + 1] = v1.y;
    b1[q * 4 + 2] = v1.z; b1[q * 4 + 3] = v1.w;
  }

  const float4* wg = reinterpret_cast<const float4*>(&w[(size_t)tbase * RANK]);
#pragma unroll
  for (int jj = 0; jj < 2; ++jj) {
    const int slot = tid + 256 * jj;  // 512 float4 slots
    reinterpret_cast<float4*>(wl)[slot] = wg[slot];
  }
  __syncthreads();

#pragma unroll 4
  for (int tt = 0; tt < K3_TOK; ++tt) {
    float s0 = 0.f, s1 = 0.f;
#pragma unroll
    for (int q = 0; q < RANK / 4; ++q) {
      const float4 wv = reinterpret_cast<const float4*>(wl)[tt * 8 + q];
      s0 = fmaf(wv.x, b0[q * 4 + 0], s0); s1 = fmaf(wv.x, b1[q * 4 + 0], s1);
      s0 = fmaf(wv.y, b0[q * 4 + 1], s0); s1 = fmaf(wv.y, b1[q * 4 + 1], s1);
      s0 = fmaf(wv.z, b0[q * 4 + 2], s0); s1 = fmaf(wv.z, b1[q * 4 + 2], s1);
      s0 = fmaf(wv.w, b0[q * 4 + 3], s0); s1 = fmaf(wv.w, b1[q * 4 + 3], s1);
    }
    float2 o;
    o.x = s0;
    o.y = s1;
    *reinterpret_cast<float2*>(&out[(size_t)(tbase + tt) * DDIM + c0]) = o;
  }
}

extern "C" void kernel_launch(void* const* d_in, const int* in_sizes, int n_in,
                              void* d_out, int out_size, void* d_ws,
                              size_t ws_size, hipStream_t stream) {
  const float* x = (const float*)d_in[0];
  const float* A = (const float*)d_in[1];
  const float* B = (const float*)d_in[2];
  const float* dbias = (const float*)d_in[3];
  float* out = (float*)d_out;

  const size_t plane = (size_t)TOKENS * RANK;   // 512K floats = 2 MB
  float* y_part = (float*)d_ws;                 // KCH planes (16 MB)
  float* w = y_part + (size_t)KCH * plane;      // 1 plane (2 MB)
  ushort* Ah = (ushort*)(w + plane);            // 256 KB
  ushort* Al = Ah + (size_t)RANK * DDIM;        // 256 KB
  int* flag = (int*)(Al + (size_t)RANK * DDIM); // 64 KB, fully rewritten by k2

  // NOTE: no hipMemsetAsync in the graph — the 4-byte fill node showed up as
  // ~158 us/replay fillBufferAligned dispatches in the r10 profile.

  k0_splitA<<<(RANK * DDIM) / 256, 256, 0, stream>>>(A, Ah, Al);
  k1_mfma<<<dim3(TOKENS / 64, KCH), 256, 0, stream>>>(x, Ah, Al, y_part);
  k2_topk<<<TOKENS / 64, 64, 0, stream>>>(y_part, dbias, w, flag);
  k2b_refine<<<TOKENS / 16, 64, 0, stream>>>(x, A, dbias, flag, w);
  k3_out<<<dim3(DDIM / 512, TOKENS / K3_TOK), 256, 0, stream>>>(w, B, out);
}

// Round 12
// 249.601 us; speedup vs baseline: 1.4044x; 1.4044x over previous
//
#include <hip/hip_runtime.h>

#define TOKENS 16384
#define DDIM 4096
#define RANK 32
#define TOPK 8
#define KCH 8                        // K-chunks -> y_part planes
#define KSTEPS ((DDIM / KCH) / 32)   // 16 MFMA K-steps per chunk
#define TAU 2e-3f                    // routing-gap margin: flag if below

typedef __attribute__((ext_vector_type(8))) short bf16x8;  // 8 bf16 (4 VGPR)
typedef __attribute__((ext_vector_type(4))) float f32x4;

// ---------------- K0: split A into hi/lo bf16; zero the flag counter ------
// Zeroing here (instead of hipMemsetAsync) keeps the 155us/replay
// fillBufferAligned node out of the graph (r10 lesson). k0 completes before
// k2 in stream order, so the counter is 0 when k2's atomics begin.
__global__ __launch_bounds__(256) void k0_splitA(const float* __restrict__ A,
                                                 ushort* __restrict__ Ah,
                                                 ushort* __restrict__ Al,
                                                 int* __restrict__ flag_cnt) {
  const int i = blockIdx.x * 256 + threadIdx.x;  // 0 .. RANK*DDIM-1
  if (i == 0) *flag_cnt = 0;
  const float a = A[i];
  const unsigned ab = __float_as_uint(a);
  const float hf = __uint_as_float(ab & 0xFFFF0000u);
  const float r = a - hf;
  Ah[i] = (ushort)(ab >> 16);
  Al[i] = (ushort)(__float_as_uint(r) >> 16);
}

// ---------------- K1: y_part[kc][t][r] via mfma_f32_16x16x32_bf16 ----------
// y ~= xh*Ah + xh*Al + xl*Ah (delta ~1e-5). Values are plenty accurate for
// the output; ROUTING near boundaries is certified in k2, fixed in k2b.
__global__ __launch_bounds__(256) void k1_mfma(const float* __restrict__ x,
                                               const ushort* __restrict__ Ah,
                                               const ushort* __restrict__ Al,
                                               float* __restrict__ y_part) {
  const int tid = threadIdx.x;
  const int lane = tid & 63;
  const int wv = tid >> 6;
  const int t0 = blockIdx.x * 64 + wv * 16;
  const int kc = blockIdx.y;
  const int k0 = kc * (DDIM / KCH);

  const int mrow = lane & 15;  // token (A-op) / rank (B-op)
  const int kg = lane >> 4;    // k-group of 8 dims

  f32x4 acc0 = {0.f, 0.f, 0.f, 0.f};  // ranks 0..15
  f32x4 acc1 = {0.f, 0.f, 0.f, 0.f};  // ranks 16..31

  const float* xp = &x[(size_t)(t0 + mrow) * DDIM + k0 + kg * 8];
  const ushort* ah0 = &Ah[(size_t)mrow * DDIM + k0 + kg * 8];
  const ushort* ah1 = &Ah[(size_t)(mrow + 16) * DDIM + k0 + kg * 8];
  const ushort* al0 = &Al[(size_t)mrow * DDIM + k0 + kg * 8];
  const ushort* al1 = &Al[(size_t)(mrow + 16) * DDIM + k0 + kg * 8];

#pragma unroll 2
  for (int ks = 0; ks < KSTEPS; ++ks) {
    const float4 xa = *reinterpret_cast<const float4*>(xp + ks * 32);
    const float4 xb = *reinterpret_cast<const float4*>(xp + ks * 32 + 4);
    const bf16x8 bh0 = *reinterpret_cast<const bf16x8*>(ah0 + ks * 32);
    const bf16x8 bh1 = *reinterpret_cast<const bf16x8*>(ah1 + ks * 32);
    const bf16x8 bl0 = *reinterpret_cast<const bf16x8*>(al0 + ks * 32);
    const bf16x8 bl1 = *reinterpret_cast<const bf16x8*>(al1 + ks * 32);

    const float xf[8] = {xa.x, xa.y, xa.z, xa.w, xb.x, xb.y, xb.z, xb.w};
    bf16x8 xh, xl;
#pragma unroll
    for (int j = 0; j < 8; ++j) {  // constant indices only (no scratch)
      const unsigned b = __float_as_uint(xf[j]);
      xh[j] = (short)(b >> 16);
      const float r = xf[j] - __uint_as_float(b & 0xFFFF0000u);
      xl[j] = (short)(__float_as_uint(r) >> 16);
    }

    acc0 = __builtin_amdgcn_mfma_f32_16x16x32_bf16(xh, bh0, acc0, 0, 0, 0);
    acc1 = __builtin_amdgcn_mfma_f32_16x16x32_bf16(xh, bh1, acc1, 0, 0, 0);
    acc0 = __builtin_amdgcn_mfma_f32_16x16x32_bf16(xh, bl0, acc0, 0, 0, 0);
    acc1 = __builtin_amdgcn_mfma_f32_16x16x32_bf16(xh, bl1, acc1, 0, 0, 0);
    acc0 = __builtin_amdgcn_mfma_f32_16x16x32_bf16(xl, bh0, acc0, 0, 0, 0);
    acc1 = __builtin_amdgcn_mfma_f32_16x16x32_bf16(xl, bh1, acc1, 0, 0, 0);
  }

  // D: token = t0 + kg*4 + i, rank = mrow (acc0) / mrow+16 (acc1)
  float* yp = &y_part[((size_t)kc * TOKENS + t0 + kg * 4) * RANK + mrow];
#pragma unroll
  for (int i = 0; i < 4; ++i) {
    yp[(size_t)i * RANK] = acc0[i];
    yp[(size_t)i * RANK + 16] = acc1[i];
  }
}

// ---------------- K2: reduce, top-8 + gap margin; flag ambiguous ----------
// List SET is deterministic (order isn't, but k2b's per-token rewrite makes
// the final w deterministic regardless of order).
__global__ __launch_bounds__(64) void k2_topk(const float* __restrict__ y_part,
                                              const float* __restrict__ dbias,
                                              float* __restrict__ w,
                                              int* __restrict__ flag_cnt,
                                              int* __restrict__ flag_list) {
  const int t = blockIdx.x * 64 + threadIdx.x;
  float yv[RANK];
#pragma unroll
  for (int r = 0; r < RANK; ++r) yv[r] = 0.f;
  for (int c = 0; c < KCH; ++c) {
    const float* yp = &y_part[((size_t)c * TOKENS + t) * RANK];
#pragma unroll
    for (int q = 0; q < RANK / 4; ++q) {
      const float4 v = reinterpret_cast<const float4*>(yp)[q];
      yv[q * 4 + 0] += v.x; yv[q * 4 + 1] += v.y;
      yv[q * 4 + 2] += v.z; yv[q * 4 + 3] += v.w;
    }
  }

  float ab[RANK];
#pragma unroll
  for (int r = 0; r < RANK; ++r) ab[r] = fabsf(yv[r] + dbias[r]);

  unsigned mask = 0;
  float best8 = 0.f;
#pragma unroll
  for (int k = 0; k < TOPK; ++k) {
    float best = -1.f;
    int bi = 0;
#pragma unroll
    for (int r = 0; r < RANK; ++r) {
      // strict > keeps lowest index on ties == jax.lax.top_k stability
      const bool sel = (((mask >> r) & 1u) == 0u) && (ab[r] > best);
      best = sel ? ab[r] : best;
      bi = sel ? r : bi;
    }
    mask |= 1u << bi;
    best8 = best;
  }
  // 9th-largest: max over unselected
  float ninth = -1.f;
#pragma unroll
  for (int r = 0; r < RANK; ++r) {
    const bool un = ((mask >> r) & 1u) == 0u;
    ninth = (un && ab[r] > ninth) ? ab[r] : ninth;
  }
  if (best8 - ninth < TAU) {  // split-y can't certify fp32 decision
    const int idx = atomicAdd(flag_cnt, 1);
    flag_list[idx] = t;
  }

  float* wp = &w[(size_t)t * RANK];
#pragma unroll
  for (int q = 0; q < RANK / 4; ++q) {
    float4 o;
    o.x = ((mask >> (q * 4 + 0)) & 1u) ? 2.0f * yv[q * 4 + 0] : 0.f;
    o.y = ((mask >> (q * 4 + 1)) & 1u) ? 2.0f * yv[q * 4 + 1] : 0.f;
    o.z = ((mask >> (q * 4 + 2)) & 1u) ? 2.0f * yv[q * 4 + 2] : 0.f;
    o.w = ((mask >> (q * 4 + 3)) & 1u) ? 2.0f * yv[q * 4 + 3] : 0.f;
    reinterpret_cast<float4*>(wp)[q] = o;
  }
}

// ---------------- K2b: exact fp32 re-route for flagged tokens -------------
// 512 blocks grid-stride the list (~500 entries -> ~1 token/block, no
// straggler tail). 256 thr: rank=tid&31, seg=tid>>5 (8x512 dims), float4
// loads. Two-level fp32 sums (same risk profile as the passing fp32 rounds).
__global__ __launch_bounds__(256) void k2b_refine(
    const float* __restrict__ x, const float* __restrict__ A,
    const float* __restrict__ dbias, const int* __restrict__ flag_cnt,
    const int* __restrict__ flag_list, float* __restrict__ w) {
  __shared__ float part[8][RANK];
  __shared__ float yv_s[RANK];
  __shared__ unsigned mask_s;
  const int cnt = *flag_cnt;
  const int rank = threadIdx.x & 31;
  const int seg = threadIdx.x >> 5;

  for (int i = blockIdx.x; i < cnt; i += gridDim.x) {
    const int t = flag_list[i];
    const float4* xr =
        reinterpret_cast<const float4*>(&x[(size_t)t * DDIM + seg * 512]);
    const float4* Ar =
        reinterpret_cast<const float4*>(&A[(size_t)rank * DDIM + seg * 512]);
    float s = 0.f;
    for (int c = 0; c < 128; c += 4) {  // 16-dim sub-sums, two-level fp32
      float ss = 0.f;
#pragma unroll
      for (int u = 0; u < 4; ++u) {
        const float4 xv = xr[c + u];
        const float4 av = Ar[c + u];
        ss = fmaf(xv.x, av.x, ss);
        ss = fmaf(xv.y, av.y, ss);
        ss = fmaf(xv.z, av.z, ss);
        ss = fmaf(xv.w, av.w, ss);
      }
      s += ss;
    }
    part[seg][rank] = s;
    __syncthreads();
    if (threadIdx.x < 32) {
      float y = 0.f;
#pragma unroll
      for (int g = 0; g < 8; ++g) y += part[g][threadIdx.x];
      yv_s[threadIdx.x] = y;
    }
    __syncthreads();
    if (threadIdx.x == 0) {
      float ab[RANK];
#pragma unroll
      for (int r = 0; r < RANK; ++r) ab[r] = fabsf(yv_s[r] + dbias[r]);
      unsigned mask = 0;
#pragma unroll
      for (int k = 0; k < TOPK; ++k) {
        float best = -1.f;
        int bi = 0;
#pragma unroll
        for (int r = 0; r < RANK; ++r) {
          const bool sel = (((mask >> r) & 1u) == 0u) && (ab[r] > best);
          best = sel ? ab[r] : best;
          bi = sel ? r : bi;
        }
        mask |= 1u << bi;
      }
      mask_s = mask;
    }
    __syncthreads();
    if (threadIdx.x < 32) {
      w[(size_t)t * RANK + rank] =
          ((mask_s >> rank) & 1u) ? 2.0f * yv_s[rank] : 0.f;
    }
    __syncthreads();  // protect LDS reuse next iteration
  }
}

// ---------------- K3: out[t][o] = sum_r w[t][r] * B[o][r] ----------------
#define K3_TOK 64

__global__ __launch_bounds__(256) void k3_out(const float* __restrict__ w,
                                              const float* __restrict__ B,
                                              float* __restrict__ out) {
  const int tid = threadIdx.x;
  const int c0 = blockIdx.x * 512 + tid * 2;
  const int tbase = blockIdx.y * K3_TOK;

  __shared__ float wl[K3_TOK * RANK];  // 8 KB

  float b0[RANK], b1[RANK];
#pragma unroll
  for (int q = 0; q < RANK / 4; ++q) {
    const float4 v0 = reinterpret_cast<const float4*>(&B[(size_t)c0 * RANK])[q];
    const float4 v1 =
        reinterpret_cast<const float4*>(&B[(size_t)(c0 + 1) * RANK])[q];
    b0[q * 4 + 0] = v0.x; b0[q * 4 + 1] = v0.y;
    b0[q * 4 + 2] = v0.z; b0[q * 4 + 3] = v0.w;
    b1[q * 4 + 0] = v1.x; b1[q * 4 + 1] = v1.y;
    b1[q * 4 + 2] = v1.z; b1[q * 4 + 3] = v1.w;
  }

  const float4* wg = reinterpret_cast<const float4*>(&w[(size_t)tbase * RANK]);
#pragma unroll
  for (int jj = 0; jj < 2; ++jj) {
    const int slot = tid + 256 * jj;  // 512 float4 slots
    reinterpret_cast<float4*>(wl)[slot] = wg[slot];
  }
  __syncthreads();

#pragma unroll 4
  for (int tt = 0; tt < K3_TOK; ++tt) {
    float s0 = 0.f, s1 = 0.f;
#pragma unroll
    for (int q = 0; q < RANK / 4; ++q) {
      const float4 wv = reinterpret_cast<const float4*>(wl)[tt * 8 + q];
      s0 = fmaf(wv.x, b0[q * 4 + 0], s0); s1 = fmaf(wv.x, b1[q * 4 + 0], s1);
      s0 = fmaf(wv.y, b0[q * 4 + 1], s0); s1 = fmaf(wv.y, b1[q * 4 + 1], s1);
      s0 = fmaf(wv.z, b0[q * 4 + 2], s0); s1 = fmaf(wv.z, b1[q * 4 + 2], s1);
      s0 = fmaf(wv.w, b0[q * 4 + 3], s0); s1 = fmaf(wv.w, b1[q * 4 + 3], s1);
    }
    float2 o;
    o.x = s0;
    o.y = s1;
    *reinterpret_cast<float2*>(&out[(size_t)(tbase + tt) * DDIM + c0]) = o;
  }
}

extern "C" void kernel_launch(void* const* d_in, const int* in_sizes, int n_in,
                              void* d_out, int out_size, void* d_ws,
                              size_t ws_size, hipStream_t stream) {
  const float* x = (const float*)d_in[0];
  const float* A = (const float*)d_in[1];
  const float* B = (const float*)d_in[2];
  const float* dbias = (const float*)d_in[3];
  float* out = (float*)d_out;

  const size_t plane = (size_t)TOKENS * RANK;   // 512K floats = 2 MB
  float* y_part = (float*)d_ws;                 // KCH planes (16 MB)
  float* w = y_part + (size_t)KCH * plane;      // 1 plane (2 MB)
  ushort* Ah = (ushort*)(w + plane);            // 256 KB
  ushort* Al = Ah + (size_t)RANK * DDIM;        // 256 KB
  int* flag_cnt = (int*)(Al + (size_t)RANK * DDIM);
  int* flag_list = flag_cnt + 4;                // capacity TOKENS (64 KB)

  k0_splitA<<<(RANK * DDIM) / 256, 256, 0, stream>>>(A, Ah, Al, flag_cnt);
  k1_mfma<<<dim3(TOKENS / 64, KCH), 256, 0, stream>>>(x, Ah, Al, y_part);
  k2_topk<<<TOKENS / 64, 64, 0, stream>>>(y_part, dbias, w, flag_cnt,
                                          flag_list);
  k2b_refine<<<512, 256, 0, stream>>>(x, A, dbias, flag_cnt, flag_list, w);
  k3_out<<<dim3(DDIM / 512, TOKENS / K3_TOK), 256, 0, stream>>>(w, B, out);
}

// Round 13
// 249.503 us; speedup vs baseline: 1.4049x; 1.0004x over previous
//
#include <hip/hip_runtime.h>

#define TOKENS 16384
#define DDIM 4096
#define RANK 32
#define TOPK 8
#define KCH 8                        // K-chunks -> y_part planes
#define KSTEPS ((DDIM / KCH) / 32)   // 16 MFMA K-steps per chunk
#define TAU 2e-3f                    // routing-gap margin: flag if below

typedef __attribute__((ext_vector_type(8))) short bf16x8;  // 8 bf16 (4 VGPR)
typedef __attribute__((ext_vector_type(4))) float f32x4;

// ---------------- K0: split A into hi/lo bf16; zero the flag counter ------
// Zeroing here (instead of hipMemsetAsync) keeps the 155us/replay
// fillBufferAligned node out of the graph (r10 lesson). k0 completes before
// k2 in stream order, so the counter is 0 when k2's atomics begin.
__global__ __launch_bounds__(256) void k0_splitA(const float* __restrict__ A,
                                                 ushort* __restrict__ Ah,
                                                 ushort* __restrict__ Al,
                                                 int* __restrict__ flag_cnt) {
  const int i = blockIdx.x * 256 + threadIdx.x;  // 0 .. RANK*DDIM-1
  if (i == 0) *flag_cnt = 0;
  const float a = A[i];
  const unsigned ab = __float_as_uint(a);
  const float hf = __uint_as_float(ab & 0xFFFF0000u);
  const float r = a - hf;
  Ah[i] = (ushort)(ab >> 16);
  Al[i] = (ushort)(__float_as_uint(r) >> 16);
}

// ---------------- K1: y_part[kc][t][r] via mfma_f32_16x16x32_bf16 ----------
// y ~= xh*Ah + xh*Al + xl*Ah (delta ~1e-5). Values are plenty accurate for
// the output; ROUTING near boundaries is certified in k2, fixed in k2b.
__global__ __launch_bounds__(256) void k1_mfma(const float* __restrict__ x,
                                               const ushort* __restrict__ Ah,
                                               const ushort* __restrict__ Al,
                                               float* __restrict__ y_part) {
  const int tid = threadIdx.x;
  const int lane = tid & 63;
  const int wv = tid >> 6;
  const int t0 = blockIdx.x * 64 + wv * 16;
  const int kc = blockIdx.y;
  const int k0 = kc * (DDIM / KCH);

  const int mrow = lane & 15;  // token (A-op) / rank (B-op)
  const int kg = lane >> 4;    // k-group of 8 dims

  f32x4 acc0 = {0.f, 0.f, 0.f, 0.f};  // ranks 0..15
  f32x4 acc1 = {0.f, 0.f, 0.f, 0.f};  // ranks 16..31

  const float* xp = &x[(size_t)(t0 + mrow) * DDIM + k0 + kg * 8];
  const ushort* ah0 = &Ah[(size_t)mrow * DDIM + k0 + kg * 8];
  const ushort* ah1 = &Ah[(size_t)(mrow + 16) * DDIM + k0 + kg * 8];
  const ushort* al0 = &Al[(size_t)mrow * DDIM + k0 + kg * 8];
  const ushort* al1 = &Al[(size_t)(mrow + 16) * DDIM + k0 + kg * 8];

#pragma unroll 2
  for (int ks = 0; ks < KSTEPS; ++ks) {
    const float4 xa = *reinterpret_cast<const float4*>(xp + ks * 32);
    const float4 xb = *reinterpret_cast<const float4*>(xp + ks * 32 + 4);
    const bf16x8 bh0 = *reinterpret_cast<const bf16x8*>(ah0 + ks * 32);
    const bf16x8 bh1 = *reinterpret_cast<const bf16x8*>(ah1 + ks * 32);
    const bf16x8 bl0 = *reinterpret_cast<const bf16x8*>(al0 + ks * 32);
    const bf16x8 bl1 = *reinterpret_cast<const bf16x8*>(al1 + ks * 32);

    const float xf[8] = {xa.x, xa.y, xa.z, xa.w, xb.x, xb.y, xb.z, xb.w};
    bf16x8 xh, xl;
#pragma unroll
    for (int j = 0; j < 8; ++j) {  // constant indices only (no scratch)
      const unsigned b = __float_as_uint(xf[j]);
      xh[j] = (short)(b >> 16);
      const float r = xf[j] - __uint_as_float(b & 0xFFFF0000u);
      xl[j] = (short)(__float_as_uint(r) >> 16);
    }

    acc0 = __builtin_amdgcn_mfma_f32_16x16x32_bf16(xh, bh0, acc0, 0, 0, 0);
    acc1 = __builtin_amdgcn_mfma_f32_16x16x32_bf16(xh, bh1, acc1, 0, 0, 0);
    acc0 = __builtin_amdgcn_mfma_f32_16x16x32_bf16(xh, bl0, acc0, 0, 0, 0);
    acc1 = __builtin_amdgcn_mfma_f32_16x16x32_bf16(xh, bl1, acc1, 0, 0, 0);
    acc0 = __builtin_amdgcn_mfma_f32_16x16x32_bf16(xl, bh0, acc0, 0, 0, 0);
    acc1 = __builtin_amdgcn_mfma_f32_16x16x32_bf16(xl, bh1, acc1, 0, 0, 0);
  }

  // D: token = t0 + kg*4 + i, rank = mrow (acc0) / mrow+16 (acc1)
  float* yp = &y_part[((size_t)kc * TOKENS + t0 + kg * 4) * RANK + mrow];
#pragma unroll
  for (int i = 0; i < 4; ++i) {
    yp[(size_t)i * RANK] = acc0[i];
    yp[(size_t)i * RANK + 16] = acc1[i];
  }
}

// ---------------- K2: reduce, top-8 + gap margin; flag ambiguous ----------
// List SET is deterministic (order isn't, but k2b's per-token rewrite makes
// the final w deterministic regardless of order).
__global__ __launch_bounds__(64) void k2_topk(const float* __restrict__ y_part,
                                              const float* __restrict__ dbias,
                                              float* __restrict__ w,
                                              int* __restrict__ flag_cnt,
                                              int* __restrict__ flag_list) {
  const int t = blockIdx.x * 64 + threadIdx.x;
  float yv[RANK];
#pragma unroll
  for (int r = 0; r < RANK; ++r) yv[r] = 0.f;
  for (int c = 0; c < KCH; ++c) {
    const float* yp = &y_part[((size_t)c * TOKENS + t) * RANK];
#pragma unroll
    for (int q = 0; q < RANK / 4; ++q) {
      const float4 v = reinterpret_cast<const float4*>(yp)[q];
      yv[q * 4 + 0] += v.x; yv[q * 4 + 1] += v.y;
      yv[q * 4 + 2] += v.z; yv[q * 4 + 3] += v.w;
    }
  }

  float ab[RANK];
#pragma unroll
  for (int r = 0; r < RANK; ++r) ab[r] = fabsf(yv[r] + dbias[r]);

  unsigned mask = 0;
  float best8 = 0.f;
#pragma unroll
  for (int k = 0; k < TOPK; ++k) {
    float best = -1.f;
    int bi = 0;
#pragma unroll
    for (int r = 0; r < RANK; ++r) {
      // strict > keeps lowest index on ties == jax.lax.top_k stability
      const bool sel = (((mask >> r) & 1u) == 0u) && (ab[r] > best);
      best = sel ? ab[r] : best;
      bi = sel ? r : bi;
    }
    mask |= 1u << bi;
    best8 = best;
  }
  // 9th-largest: max over unselected
  float ninth = -1.f;
#pragma unroll
  for (int r = 0; r < RANK; ++r) {
    const bool un = ((mask >> r) & 1u) == 0u;
    ninth = (un && ab[r] > ninth) ? ab[r] : ninth;
  }
  if (best8 - ninth < TAU) {  // split-y can't certify fp32 decision
    const int idx = atomicAdd(flag_cnt, 1);
    flag_list[idx] = t;
  }

  float* wp = &w[(size_t)t * RANK];
#pragma unroll
  for (int q = 0; q < RANK / 4; ++q) {
    float4 o;
    o.x = ((mask >> (q * 4 + 0)) & 1u) ? 2.0f * yv[q * 4 + 0] : 0.f;
    o.y = ((mask >> (q * 4 + 1)) & 1u) ? 2.0f * yv[q * 4 + 1] : 0.f;
    o.z = ((mask >> (q * 4 + 2)) & 1u) ? 2.0f * yv[q * 4 + 2] : 0.f;
    o.w = ((mask >> (q * 4 + 3)) & 1u) ? 2.0f * yv[q * 4 + 3] : 0.f;
    reinterpret_cast<float4*>(wp)[q] = o;
  }
}

// ---------------- K2b: exact fp32 re-route for flagged tokens -------------
// 512 blocks grid-stride the list (~500 entries -> ~1 token/block, no
// straggler tail). 256 thr: rank=tid&31, seg=tid>>5 (8x512 dims), float4
// loads. Two-level fp32 sums (same risk profile as the passing fp32 rounds).
__global__ __launch_bounds__(256) void k2b_refine(
    const float* __restrict__ x, const float* __restrict__ A,
    const float* __restrict__ dbias, const int* __restrict__ flag_cnt,
    const int* __restrict__ flag_list, float* __restrict__ w) {
  __shared__ float part[8][RANK];
  __shared__ float yv_s[RANK];
  __shared__ unsigned mask_s;
  const int cnt = *flag_cnt;
  const int rank = threadIdx.x & 31;
  const int seg = threadIdx.x >> 5;

  for (int i = blockIdx.x; i < cnt; i += gridDim.x) {
    const int t = flag_list[i];
    const float4* xr =
        reinterpret_cast<const float4*>(&x[(size_t)t * DDIM + seg * 512]);
    const float4* Ar =
        reinterpret_cast<const float4*>(&A[(size_t)rank * DDIM + seg * 512]);
    float s = 0.f;
    for (int c = 0; c < 128; c += 4) {  // 16-dim sub-sums, two-level fp32
      float ss = 0.f;
#pragma unroll
      for (int u = 0; u < 4; ++u) {
        const float4 xv = xr[c + u];
        const float4 av = Ar[c + u];
        ss = fmaf(xv.x, av.x, ss);
        ss = fmaf(xv.y, av.y, ss);
        ss = fmaf(xv.z, av.z, ss);
        ss = fmaf(xv.w, av.w, ss);
      }
      s += ss;
    }
    part[seg][rank] = s;
    __syncthreads();
    if (threadIdx.x < 32) {
      float y = 0.f;
#pragma unroll
      for (int g = 0; g < 8; ++g) y += part[g][threadIdx.x];
      yv_s[threadIdx.x] = y;
    }
    __syncthreads();
    if (threadIdx.x == 0) {
      float ab[RANK];
#pragma unroll
      for (int r = 0; r < RANK; ++r) ab[r] = fabsf(yv_s[r] + dbias[r]);
      unsigned mask = 0;
#pragma unroll
      for (int k = 0; k < TOPK; ++k) {
        float best = -1.f;
        int bi = 0;
#pragma unroll
        for (int r = 0; r < RANK; ++r) {
          const bool sel = (((mask >> r) & 1u) == 0u) && (ab[r] > best);
          best = sel ? ab[r] : best;
          bi = sel ? r : bi;
        }
        mask |= 1u << bi;
      }
      mask_s = mask;
    }
    __syncthreads();
    if (threadIdx.x < 32) {
      w[(size_t)t * RANK + rank] =
          ((mask_s >> rank) & 1u) ? 2.0f * yv_s[rank] : 0.f;
    }
    __syncthreads();  // protect LDS reuse next iteration
  }
}

// ---------------- K3: out[t][o] = sum_r w[t][r] * B[o][r] ----------------
#define K3_TOK 64

__global__ __launch_bounds__(256) void k3_out(const float* __restrict__ w,
                                              const float* __restrict__ B,
                                              float* __restrict__ out) {
  const int tid = threadIdx.x;
  const int c0 = blockIdx.x * 512 + tid * 2;
  const int tbase = blockIdx.y * K3_TOK;

  __shared__ float wl[K3_TOK * RANK];  // 8 KB

  float b0[RANK], b1[RANK];
#pragma unroll
  for (int q = 0; q < RANK / 4; ++q) {
    const float4 v0 = reinterpret_cast<const float4*>(&B[(size_t)c0 * RANK])[q];
    const float4 v1 =
        reinterpret_cast<const float4*>(&B[(size_t)(c0 + 1) * RANK])[q];
    b0[q * 4 + 0] = v0.x; b0[q * 4 + 1] = v0.y;
    b0[q * 4 + 2] = v0.z; b0[q * 4 + 3] = v0.w;
    b1[q * 4 + 0] = v1.x; b1[q * 4 + 1] = v1.y;
    b1[q * 4 + 2] = v1.z; b1[q * 4 + 3] = v1.w;
  }

  const float4* wg = reinterpret_cast<const float4*>(&w[(size_t)tbase * RANK]);
#pragma unroll
  for (int jj = 0; jj < 2; ++jj) {
    const int slot = tid + 256 * jj;  // 512 float4 slots
    reinterpret_cast<float4*>(wl)[slot] = wg[slot];
  }
  __syncthreads();

#pragma unroll 4
  for (int tt = 0; tt < K3_TOK; ++tt) {
    float s0 = 0.f, s1 = 0.f;
#pragma unroll
    for (int q = 0; q < RANK / 4; ++q) {
      const float4 wv = reinterpret_cast<const float4*>(wl)[tt * 8 + q];
      s0 = fmaf(wv.x, b0[q * 4 + 0], s0); s1 = fmaf(wv.x, b1[q * 4 + 0], s1);
      s0 = fmaf(wv.y, b0[q * 4 + 1], s0); s1 = fmaf(wv.y, b1[q * 4 + 1], s1);
      s0 = fmaf(wv.z, b0[q * 4 + 2], s0); s1 = fmaf(wv.z, b1[q * 4 + 2], s1);
      s0 = fmaf(wv.w, b0[q * 4 + 3], s0); s1 = fmaf(wv.w, b1[q * 4 + 3], s1);
    }
    float2 o;
    o.x = s0;
    o.y = s1;
    *reinterpret_cast<float2*>(&out[(size_t)(tbase + tt) * DDIM + c0]) = o;
  }
}

extern "C" void kernel_launch(void* const* d_in, const int* in_sizes, int n_in,
                              void* d_out, int out_size, void* d_ws,
                              size_t ws_size, hipStream_t stream) {
  const float* x = (const float*)d_in[0];
  const float* A = (const float*)d_in[1];
  const float* B = (const float*)d_in[2];
  const float* dbias = (const float*)d_in[3];
  float* out = (float*)d_out;

  const size_t plane = (size_t)TOKENS * RANK;   // 512K floats = 2 MB
  float* y_part = (float*)d_ws;                 // KCH planes (16 MB)
  float* w = y_part + (size_t)KCH * plane;      // 1 plane (2 MB)
  ushort* Ah = (ushort*)(w + plane);            // 256 KB
  ushort* Al = Ah + (size_t)RANK * DDIM;        // 256 KB
  int* flag_cnt = (int*)(Al + (size_t)RANK * DDIM);
  int* flag_list = flag_cnt + 4;                // capacity TOKENS (64 KB)

  k0_splitA<<<(RANK * DDIM) / 256, 256, 0, stream>>>(A, Ah, Al, flag_cnt);
  k1_mfma<<<dim3(TOKENS / 64, KCH), 256, 0, stream>>>(x, Ah, Al, y_part);
  k2_topk<<<TOKENS / 64, 64, 0, stream>>>(y_part, dbias, w, flag_cnt,
                                          flag_list);
  k2b_refine<<<512, 256, 0, stream>>>(x, A, dbias, flag_cnt, flag_list, w);
  k3_out<<<dim3(DDIM / 512, TOKENS / K3_TOK), 256, 0, stream>>>(w, B, out);
}